// Round 7
// baseline (1054.096 us; speedup 1.0000x reference)
//
#include <hip/hip_runtime.h>
#include <stdint.h>

using u16 = unsigned short;
typedef __attribute__((ext_vector_type(8))) short bf16x8;
typedef __attribute__((ext_vector_type(4))) float f32x4;

constexpr int D  = 512;
constexpr int P  = 256;
constexpr int BM = 64;

__device__ __forceinline__ u16 f2bf(float f) {  // RNE float->bf16
  uint32_t u = __builtin_bit_cast(uint32_t, f);
  u += 0x7fffu + ((u >> 16) & 1u);
  return (u16)(u >> 16);
}

// XOR-swizzled u16 index into the 64x256 LDS tile (row stride 512B).
// Flips bits 3..5 of the 16B-chunk index -> b128 reads at fixed col,
// varying row spread across banks (G4 swizzle). Keeps 16B alignment.
__device__ __forceinline__ int swz(int row, int col) {
  return (row * 256 + col) ^ ((row & 7) << 3);
}

__device__ __forceinline__ bf16x8 pack8(const float4& a, const float4& b) {
  union { bf16x8 v; uint32_t u[4]; } r;
  r.u[0] = (uint32_t)f2bf(a.x) | ((uint32_t)f2bf(a.y) << 16);
  r.u[1] = (uint32_t)f2bf(a.z) | ((uint32_t)f2bf(a.w) << 16);
  r.u[2] = (uint32_t)f2bf(b.x) | ((uint32_t)f2bf(b.y) << 16);
  r.u[3] = (uint32_t)f2bf(b.z) | ((uint32_t)f2bf(b.w) << 16);
  return r.v;
}
__device__ __forceinline__ float dot4(const float4& v) {
  return v.x * v.x + v.y * v.y + v.z * v.z + v.w * v.w;
}

// Fragment-major B layouts: element (tile t, step s, lane l, e) at ((s*NT+t)*64+l)*8+e
// where lane l = g*16 + lrow holds B[col = t*16 + lrow][k = s*32 + g*8 + e].
// Every MFMA B-fragment load is 64 lanes x 16B fully contiguous (1KB).

// ---------------- prep kernels ----------------

__global__ void k_gate(const float* __restrict__ gl, const float* __restrict__ traw,
                       float* __restrict__ gate) {
  int l = threadIdx.x;  // 64 threads
  float t = 1.f / (1.f + expf(-traw[0]));
  t = t * (1.f - 0.001f) + 0.001f;
  float v[4];
  float m = -3.4e38f;
  #pragma unroll
  for (int i = 0; i < 4; ++i) { v[i] = gl[l + i * 64] / t; m = fmaxf(m, v[i]); }
  #pragma unroll
  for (int s = 1; s < 64; s <<= 1) m = fmaxf(m, __shfl_xor(m, s));
  float sum = 0.f;
  #pragma unroll
  for (int i = 0; i < 4; ++i) { v[i] = expf(v[i] - m); sum += v[i]; }
  #pragma unroll
  for (int s = 1; s < 64; s <<= 1) sum += __shfl_xor(sum, s);
  #pragma unroll
  for (int i = 0; i < 4; ++i) gate[l + i * 64] = v[i] / sum;
}

// entmax15 over each row k of adj_logits; writes E[k][j]*gate[j] into egF at (col=j, kk=k)
__global__ void k_adj(const float* __restrict__ adj, const float* __restrict__ gate,
                      u16* __restrict__ egF) {
  int k = blockIdx.x, l = threadIdx.x;  // 256 blocks x 64 threads
  float z[4];
  float m = -3.4e38f;
  #pragma unroll
  for (int i = 0; i < 4; ++i) { z[i] = adj[(size_t)k * P + l + i * 64] * 0.5f; m = fmaxf(m, z[i]); }
  #pragma unroll
  for (int s = 1; s < 64; s <<= 1) m = fmaxf(m, __shfl_xor(m, s));
  float lo = m - 1.f, hi = m;
  for (int it = 0; it < 26; ++it) {
    float tau = 0.5f * (lo + hi), s = 0.f;
    #pragma unroll
    for (int i = 0; i < 4; ++i) { float d = z[i] - tau; s += (d > 0.f) ? d * d : 0.f; }
    #pragma unroll
    for (int sh = 1; sh < 64; sh <<= 1) s += __shfl_xor(s, sh);
    if (s >= 1.f) lo = tau; else hi = tau;
  }
  float tau = 0.5f * (lo + hi);
  int ss = k >> 5, g = (k >> 3) & 3, e = k & 7;
  #pragma unroll
  for (int i = 0; i < 4; ++i) {
    int j = l + i * 64;
    float d = z[i] - tau;
    float p = (d > 0.f) ? d * d : 0.f;
    int tt = j >> 4, lr = j & 15;
    egF[(size_t)(((ss * 16 + tt) * 64) + g * 16 + lr) * 8 + e] = f2bf(p * gate[j]);
  }
}

// proto -> pbF (GEMM1 B: col=p, k=d) and ptF (GEMM3 B: col=d, k=p); pnorm[p] = ||proto_p||^2
__global__ void k_proto(const float* __restrict__ proto, u16* __restrict__ pbF,
                        u16* __restrict__ ptF, float* __restrict__ pnorm) {
  int p = blockIdx.x, t = threadIdx.x;  // 256 blocks x 256 threads
  int ttp = p >> 4, lrp = p & 15;                          // p as col (GEMM1)
  // threads 0..63: pbF in 16B chunks (8 consecutive d) + ssq partial
  if (t < 64) {
    int ss = t >> 2, g = t & 3;
    int d0 = ss * 32 + g * 8;
    float4 va = *(const float4*)(proto + (size_t)p * D + d0);
    float4 vb = *(const float4*)(proto + (size_t)p * D + d0 + 4);
    union { u16 h[8]; uint4 q; } pk;
    pk.h[0] = f2bf(va.x); pk.h[1] = f2bf(va.y); pk.h[2] = f2bf(va.z); pk.h[3] = f2bf(va.w);
    pk.h[4] = f2bf(vb.x); pk.h[5] = f2bf(vb.y); pk.h[6] = f2bf(vb.z); pk.h[7] = f2bf(vb.w);
    *(uint4*)&pbF[(size_t)(((ss * 16 + ttp) * 64) + g * 16 + lrp) * 8] = pk.q;
    float s = dot4(va) + dot4(vb);
    #pragma unroll
    for (int sh = 1; sh < 64; sh <<= 1) s += __shfl_xor(s, sh);
    if (t == 0) pnorm[p] = s;
  }
  // all 256 threads: ptF scatter (col=d, k=p), 2 d-values each
  int ssp = (p >> 5) & 7, gp = (p >> 3) & 3, ep = p & 7;   // p as k-index (GEMM3)
  #pragma unroll
  for (int i = 0; i < 2; ++i) {
    int d = t + i * 256;
    float v = proto[(size_t)p * D + d];
    int hf = d >> 8, tt = (d >> 4) & 15, lr = d & 15;
    ptF[(size_t)(((((hf * 8 + ssp) * 16) + tt) * 64) + gp * 16 + lr) * 8 + ep] = f2bf(v);
  }
}

// ---------------- fused main kernel (zero barriers, wave-private LDS stripes) ----------------

__global__ __launch_bounds__(256, 5)
void k_main(const float* __restrict__ x, const u16* __restrict__ pbF,
            const u16* __restrict__ ptF, const u16* __restrict__ egF,
            const float* __restrict__ pnorm,
            float* __restrict__ out_blend, float* __restrict__ out_gated) {
  __shared__ __align__(16) u16 wbuf[BM * P];   // 32768 B, XOR-swizzled; 5 blocks/CU

  int tid  = threadIdx.x;
  int brow = blockIdx.x * BM;

  int l    = tid & 63;
  int wv   = tid >> 6;        // wave id, 4 waves x 16-row stripes
  int r0   = wv * 16;
  int lrow = l & 15;
  int lk   = (l >> 4) * 8;    // k-offset within 32-wide K-step
  int lr4  = (l >> 4) * 4;    // row offset of this lane's acc quadrant

  // ---- GEMM1: dot[64][256] = x_bf16 @ proto^T ; reg ping-pong B prefetch ----
  f32x4 acc[16];
  #pragma unroll
  for (int c = 0; c < 16; ++c) acc[c] = {0.f, 0.f, 0.f, 0.f};

  const float* xrow = x + (size_t)(brow + r0 + lrow) * D + lk;
  const u16*   pbB  = pbF + (size_t)l * 8;
  float ssq = 0.f;

  bf16x8 b0[16], b1[16];
  #pragma unroll
  for (int c = 0; c < 16; ++c) b0[c] = *(const bf16x8*)(pbB + (size_t)c * 512);

  float4 A0 = *(const float4*)(xrow),      A1 = *(const float4*)(xrow + 4);
  float4 B0 = *(const float4*)(xrow + 32), B1 = *(const float4*)(xrow + 36);

  #pragma unroll 1
  for (int s = 0; s < 16; s += 2) {
    // even sub-step s: compute with b0, prefetch b1 = step s+1
    #pragma unroll
    for (int c = 0; c < 16; ++c)
      b1[c] = *(const bf16x8*)(pbB + (size_t)((s + 1) * 16 + c) * 512);
    ssq += dot4(A0) + dot4(A1);
    bf16x8 fa = pack8(A0, A1);
    if (s + 2 < 16) {
      A0 = *(const float4*)(xrow + (s + 2) * 32);
      A1 = *(const float4*)(xrow + (s + 2) * 32 + 4);
    }
    #pragma unroll
    for (int c = 0; c < 16; ++c)
      acc[c] = __builtin_amdgcn_mfma_f32_16x16x32_bf16(fa, b0[c], acc[c], 0, 0, 0);

    // odd sub-step s+1: compute with b1, prefetch b0 = step s+2
    if (s + 2 < 16) {
      #pragma unroll
      for (int c = 0; c < 16; ++c)
        b0[c] = *(const bf16x8*)(pbB + (size_t)((s + 2) * 16 + c) * 512);
    }
    ssq += dot4(B0) + dot4(B1);
    bf16x8 fb = pack8(B0, B1);
    if (s + 3 < 16) {
      B0 = *(const float4*)(xrow + (s + 3) * 32);
      B1 = *(const float4*)(xrow + (s + 3) * 32 + 4);
    }
    #pragma unroll
    for (int c = 0; c < 16; ++c)
      acc[c] = __builtin_amdgcn_mfma_f32_16x16x32_bf16(fb, b1[c], acc[c], 0, 0, 0);
  }

  // full row ssq: union over the 4 lk-groups holding the same row
  ssq += __shfl_xor(ssq, 16);
  ssq += __shfl_xor(ssq, 32);
  float xnj[4];
  #pragma unroll
  for (int j = 0; j < 4; ++j) xnj[j] = __shfl(ssq, lr4 + j);

  // prototype norms for this lane's 16 output cols (L2-resident)
  float pn[16];
  #pragma unroll
  for (int c = 0; c < 16; ++c) pn[c] = pnorm[c * 16 + lrow];

  // ---- z = -0.5*sqrt(clip(xn - 2*dot + pn, 0)) in place ----
  #pragma unroll
  for (int c = 0; c < 16; ++c) {
    #pragma unroll
    for (int j = 0; j < 4; ++j) {
      float sq = xnj[j] - 2.f * acc[c][j] + pn[c];
      acc[c][j] = -0.5f * sqrtf(fmaxf(sq, 0.f));
    }
  }

  // preload GEMM2 step-0 B frags; they ride through the bisection (pure VALU)
  const u16* egB = egF + (size_t)l * 8;
  #pragma unroll
  for (int c = 0; c < 16; ++c) b0[c] = *(const bf16x8*)(egB + (size_t)c * 512);

  // ---- entmax15: bisection fully in registers (4 rows/lane, reduce over 16-lane group) ----
  float mj[4] = {-3.4e38f, -3.4e38f, -3.4e38f, -3.4e38f};
  #pragma unroll
  for (int c = 0; c < 16; ++c) {
    #pragma unroll
    for (int j = 0; j < 4; ++j) mj[j] = fmaxf(mj[j], acc[c][j]);
  }
  #pragma unroll
  for (int j = 0; j < 4; ++j) {
    mj[j] = fmaxf(mj[j], __shfl_xor(mj[j], 1));
    mj[j] = fmaxf(mj[j], __shfl_xor(mj[j], 2));
    mj[j] = fmaxf(mj[j], __shfl_xor(mj[j], 4));
    mj[j] = fmaxf(mj[j], __shfl_xor(mj[j], 8));
  }
  float lo[4], hi[4];
  #pragma unroll
  for (int j = 0; j < 4; ++j) { lo[j] = mj[j] - 1.f; hi[j] = mj[j]; }

  for (int it = 0; it < 18; ++it) {
    float tau[4], s[4];
    #pragma unroll
    for (int j = 0; j < 4; ++j) { tau[j] = 0.5f * (lo[j] + hi[j]); s[j] = 0.f; }
    #pragma unroll
    for (int c = 0; c < 16; ++c) {
      #pragma unroll
      for (int j = 0; j < 4; ++j) {
        float d = fmaxf(acc[c][j] - tau[j], 0.f);
        s[j] = fmaf(d, d, s[j]);
      }
    }
    #pragma unroll
    for (int j = 0; j < 4; ++j) {
      s[j] += __shfl_xor(s[j], 1);
      s[j] += __shfl_xor(s[j], 2);
      s[j] += __shfl_xor(s[j], 4);
      s[j] += __shfl_xor(s[j], 8);
      bool ge = (s[j] >= 1.f);
      lo[j] = ge ? tau[j] : lo[j];
      hi[j] = ge ? hi[j] : tau[j];
    }
  }

  // ---- weights -> bf16 -> LDS (wave-private swizzled stripe) ----
  {
    float tau[4];
    #pragma unroll
    for (int j = 0; j < 4; ++j) tau[j] = 0.5f * (lo[j] + hi[j]);
    #pragma unroll
    for (int c = 0; c < 16; ++c) {
      #pragma unroll
      for (int j = 0; j < 4; ++j) {
        float d = fmaxf(acc[c][j] - tau[j], 0.f);
        wbuf[swz(r0 + lr4 + j, c * 16 + lrow)] = f2bf(d * d);
      }
    }
  }

  // ---- GEMM2: routed_g[64][256] = w @ E_g ; reg ping-pong B prefetch ----
  f32x4 acc2[16];
  #pragma unroll
  for (int c = 0; c < 16; ++c) acc2[c] = {0.f, 0.f, 0.f, 0.f};

  #pragma unroll 1
  for (int s = 0; s < 8; s += 2) {
    #pragma unroll
    for (int c = 0; c < 16; ++c)
      b1[c] = *(const bf16x8*)(egB + (size_t)((s + 1) * 16 + c) * 512);
    bf16x8 a0 = *(const bf16x8*)&wbuf[swz(r0 + lrow, s * 32 + lk)];
    #pragma unroll
    for (int c = 0; c < 16; ++c)
      acc2[c] = __builtin_amdgcn_mfma_f32_16x16x32_bf16(a0, b0[c], acc2[c], 0, 0, 0);

    if (s + 2 < 8) {
      #pragma unroll
      for (int c = 0; c < 16; ++c)
        b0[c] = *(const bf16x8*)(egB + (size_t)((s + 2) * 16 + c) * 512);
    }
    bf16x8 a1 = *(const bf16x8*)&wbuf[swz(r0 + lrow, (s + 1) * 32 + lk)];
    #pragma unroll
    for (int c = 0; c < 16; ++c)
      acc2[c] = __builtin_amdgcn_mfma_f32_16x16x32_bf16(a1, b1[c], acc2[c], 0, 0, 0);
  }

  // ---- row-normalize: gated = routed_g / (rowsum + 1e-8) ----
  float part[4] = {0.f, 0.f, 0.f, 0.f};
  #pragma unroll
  for (int c = 0; c < 16; ++c) {
    #pragma unroll
    for (int j = 0; j < 4; ++j) part[j] += acc2[c][j];
  }
  #pragma unroll
  for (int j = 0; j < 4; ++j) {
    part[j] += __shfl_xor(part[j], 1);
    part[j] += __shfl_xor(part[j], 2);
    part[j] += __shfl_xor(part[j], 4);
    part[j] += __shfl_xor(part[j], 8);
    part[j] = 1.f / (part[j] + 1e-8f);
  }

  // preload GEMM3 half-0 step-0 B frags (ride through gated write)
  const u16* ptB = ptF + (size_t)l * 8;
  #pragma unroll
  for (int c = 0; c < 16; ++c) b0[c] = *(const bf16x8*)(ptB + (size_t)c * 512);

  #pragma unroll
  for (int c = 0; c < 16; ++c) {
    int col = c * 16 + lrow;
    #pragma unroll
    for (int j = 0; j < 4; ++j) {
      int row = r0 + lr4 + j;
      float g = acc2[c][j] * part[j];
      out_gated[(size_t)(brow + row) * P + col] = g;
      wbuf[swz(row, col)] = f2bf(g);   // same wave-private stripe; w is dead
    }
  }

  // ---- GEMM3: blended[64][512] = gated @ proto ----
  // half 0 (cols 0..255)
  f32x4 acc3[16];
  #pragma unroll
  for (int c = 0; c < 16; ++c) acc3[c] = {0.f, 0.f, 0.f, 0.f};
  #pragma unroll 1
  for (int s = 0; s < 8; s += 2) {
    #pragma unroll
    for (int c = 0; c < 16; ++c)
      b1[c] = *(const bf16x8*)(ptB + (size_t)((s + 1) * 16 + c) * 512);
    bf16x8 a0 = *(const bf16x8*)&wbuf[swz(r0 + lrow, s * 32 + lk)];
    #pragma unroll
    for (int c = 0; c < 16; ++c)
      acc3[c] = __builtin_amdgcn_mfma_f32_16x16x32_bf16(a0, b0[c], acc3[c], 0, 0, 0);
    if (s + 2 < 8) {
      #pragma unroll
      for (int c = 0; c < 16; ++c)
        b0[c] = *(const bf16x8*)(ptB + (size_t)((s + 2) * 16 + c) * 512);
    }
    bf16x8 a1 = *(const bf16x8*)&wbuf[swz(r0 + lrow, (s + 1) * 32 + lk)];
    #pragma unroll
    for (int c = 0; c < 16; ++c)
      acc3[c] = __builtin_amdgcn_mfma_f32_16x16x32_bf16(a1, b1[c], acc3[c], 0, 0, 0);
  }
  // preload half-1 step-0 before the store epilogue (stores don't consume b0)
  #pragma unroll
  for (int c = 0; c < 16; ++c)
    b0[c] = *(const bf16x8*)(ptB + (size_t)(8 * 16 + c) * 512);
  #pragma unroll
  for (int c = 0; c < 16; ++c) {
    int dcol = c * 16 + lrow;
    #pragma unroll
    for (int j = 0; j < 4; ++j)
      out_blend[(size_t)(brow + r0 + lr4 + j) * D + dcol] = acc3[c][j];
  }

  // half 1 (cols 256..511)
  #pragma unroll
  for (int c = 0; c < 16; ++c) acc3[c] = {0.f, 0.f, 0.f, 0.f};
  #pragma unroll 1
  for (int s = 0; s < 8; s += 2) {
    #pragma unroll
    for (int c = 0; c < 16; ++c)
      b1[c] = *(const bf16x8*)(ptB + (size_t)((8 + s + 1) * 16 + c) * 512);
    bf16x8 a0 = *(const bf16x8*)&wbuf[swz(r0 + lrow, s * 32 + lk)];
    #pragma unroll
    for (int c = 0; c < 16; ++c)
      acc3[c] = __builtin_amdgcn_mfma_f32_16x16x32_bf16(a0, b0[c], acc3[c], 0, 0, 0);
    if (s + 2 < 8) {
      #pragma unroll
      for (int c = 0; c < 16; ++c)
        b0[c] = *(const bf16x8*)(ptB + (size_t)((8 + s + 2) * 16 + c) * 512);
    }
    bf16x8 a1 = *(const bf16x8*)&wbuf[swz(r0 + lrow, (s + 1) * 32 + lk)];
    #pragma unroll
    for (int c = 0; c < 16; ++c)
      acc3[c] = __builtin_amdgcn_mfma_f32_16x16x32_bf16(a1, b1[c], acc3[c], 0, 0, 0);
  }
  #pragma unroll
  for (int c = 0; c < 16; ++c) {
    int dcol = 256 + c * 16 + lrow;
    #pragma unroll
    for (int j = 0; j < 4; ++j)
      out_blend[(size_t)(brow + r0 + lr4 + j) * D + dcol] = acc3[c][j];
  }
}

// ---------------- launcher ----------------

extern "C" void kernel_launch(void* const* d_in, const int* in_sizes, int n_in,
                              void* d_out, int out_size, void* d_ws, size_t ws_size,
                              hipStream_t stream) {
  const float* x     = (const float*)d_in[0];
  const float* proto = (const float*)d_in[1];
  const float* adj   = (const float*)d_in[2];
  const float* gl    = (const float*)d_in[3];
  const float* traw  = (const float*)d_in[4];
  int N = in_sizes[0] / D;  // 65536

  u16*   pbF   = (u16*)d_ws;                  // [16][16][64][8] bf16  GEMM1 B (256 KB)
  u16*   ptF   = pbF + (size_t)P * D;         // [2][8][16][64][8]     GEMM3 B (256 KB)
  u16*   egF   = ptF + (size_t)D * P;         // [8][16][64][8]        GEMM2 B (128 KB)
  float* pnorm = (float*)(egF + (size_t)P * P);
  float* gate  = pnorm + P;

  float* out_blend = (float*)d_out;
  float* out_gated = out_blend + (size_t)N * D;

  k_gate<<<1, 64, 0, stream>>>(gl, traw, gate);
  k_proto<<<P, 256, 0, stream>>>(proto, pbF, ptF, pnorm);
  k_adj<<<P, 64, 0, stream>>>(adj, gate, egF);
  k_main<<<N / BM, 256, 0, stream>>>(x, pbF, ptF, egF, pnorm, out_blend, out_gated);
}